// Round 6
// baseline (127.282 us; speedup 1.0000x reference)
//
#include <hip/hip_runtime.h>
#include <hip/hip_cooperative_groups.h>

// TensorTree collapsed to multilinear table: out[b,u] = w1(b)^T T_u w2(b),
//   out[b,u] = sum_c K[b][c] * T[u][c],  c = q*16+p,  K[c] = w1[p]*w2[q]
// Round 9: single cooperative kernel. R5 decomposition: eval ~11.6 us,
// fill 41 us (harness), and ~31 us of precompute + TWO launch gaps +
// memset train. Fusion removes one launch boundary and the cold T
// round-trip:
//  - grid 256 blocks x 512 threads = exactly 1 block/CU;
//    __launch_bounds__(512,2) -> 2 waves/SIMD, VGPR<=256, LDS 27.6 KB.
//  - blocks 0..31: T-precompute (unchanged math); grid.sync();
//    all blocks: R5 eval body, identical work map (8 waves: wid&3 -> gw,
//    wid>>2 -> ubase). Numerics bit-identical to R5 (absmax 0.25).
// Precision: K=ah+al, T=Thi+Tlo, 3 MFMA products (al*bl dropped, ~2^-16).

namespace cg = cooperative_groups;

#define BB 65536
#define FF 8
#define DD 2
#define RR 10
#define UU 32

typedef __attribute__((ext_vector_type(8))) short short8;
typedef __attribute__((ext_vector_type(4))) float f32x4;
typedef __attribute__((ext_vector_type(4))) unsigned int u32x4;

__device__ __forceinline__ unsigned short f2bf_trunc(float x) {
    return (unsigned short)(__builtin_bit_cast(unsigned int, x) >> 16);
}
__device__ __forceinline__ float bf2f(unsigned short h) {
    return __builtin_bit_cast(float, ((unsigned int)h) << 16);
}
__device__ __forceinline__ unsigned int bcu(float x) {
    return __builtin_bit_cast(unsigned int, x);
}
__device__ __forceinline__ float bcf(unsigned int x) {
    return __builtin_bit_cast(float, x);
}

#define NWAVE 1024   // waves per unit-group = 256 blocks * 4
#define ITER  4

__global__ __launch_bounds__(512, 2) void fused_tree(
    const float* __restrict__ X,
    const float* __restrict__ core11, const float* __restrict__ core12,
    const float* __restrict__ core13, const float* __restrict__ core14,
    const float* __restrict__ core21, const float* __restrict__ core22,
    const float* __restrict__ FM, const float* __restrict__ MT,
    unsigned short* __restrict__ Thi, unsigned short* __restrict__ Tlo,
    float* __restrict__ out)
{
    const int tid = threadIdx.x;   // 0..511
    const int bid = blockIdx.x;    // 0..255

    __shared__ float sC[6][RR * RR * RR];  // staged cores, 24 KB
    __shared__ float sMT[RR * RR];
    __shared__ float sLeaf[FF][2][RR];   // [leaf][basis][r]
    __shared__ float sP[4][4][RR];       // [pair][combo(a_lo + 2*a_hi)][j]
    __shared__ float sQ[2][16][RR];      // [side][combo][j]
    __shared__ float sR1[16][RR];        // Q1 . MT

    // ================= phase 1: T precompute (blocks 0..31) =================
    if (bid < UU) {
        const int u = bid;

        // stage cores + MT into LDS, coalesced (1000 elems, 512 threads).
#pragma unroll
        for (int r = 0; r < 2; ++r) {
            const int o = tid + 512 * r;
            if (o < RR * RR * RR) {
                sC[0][o] = core11[o];
                sC[1][o] = core12[o];
                sC[2][o] = core13[o];
                sC[3][o] = core14[o];
                sC[4][o] = core21[o];
                sC[5][o] = core22[o];
            }
        }
        if (tid < RR * RR) sMT[tid] = MT[tid];

        // leaf basis vectors. leaf[f][a][r] = FM[a, r, f, u]
        if (tid < FF * 2 * RR) {             // 160 tasks
            const int f = tid / (2 * RR);
            const int rem = tid % (2 * RR);
            const int a = rem / RR;
            const int r = rem % RR;
            sLeaf[f][a][r] = FM[((a * RR + r) * FF + f) * UU + u];
        }
        __syncthreads();

        // level-1 pairs. 4 pairs x 4 combos x RR j = 160 tasks.
        if (tid < 4 * 4 * RR) {
            const int P   = tid / (4 * RR);
            const int rem = tid % (4 * RR);
            const int s   = rem / RR;              // combo: a_lo + 2*a_hi
            const int j   = rem % RR;
            const int fa = 2 * P, fb = 2 * P + 1;
            const int ai = s & 1, bi = s >> 1;
            const float* cp = sC[P];
            float a[RR], b[RR];
#pragma unroll
            for (int i = 0; i < RR; ++i) { a[i] = sLeaf[fa][ai][i]; b[i] = sLeaf[fb][bi][i]; }
            float acc0 = 0.0f, acc1 = 0.0f;
#pragma unroll
            for (int i = 0; i < RR; ++i) {
#pragma unroll
                for (int k = 0; k < RR; ++k) {
                    const float w = a[i] * b[k];
                    const float c = cp[(i * RR + k) * RR + j];
                    if (i & 1) acc1 = fmaf(w, c, acc1);
                    else       acc0 = fmaf(w, c, acc0);
                }
            }
            sP[P][s][j] = acc0 + acc1;
        }
        __syncthreads();

        // level-2. 2 sides x 16 combos x RR j = 320 tasks (single round).
        if (tid < 2 * 16 * RR) {
            const int side  = tid / (16 * RR);
            const int rem   = tid % (16 * RR);
            const int combo = rem / RR;
            const int j     = rem % RR;
            const int pa = side * 2, pb = side * 2 + 1;
            const float* cp = sC[4 + side];
            float a[RR], b[RR];
#pragma unroll
            for (int i = 0; i < RR; ++i) {
                a[i] = sP[pa][combo & 3][i];
                b[i] = sP[pb][combo >> 2][i];
            }
            float acc0 = 0.0f, acc1 = 0.0f;
#pragma unroll
            for (int i = 0; i < RR; ++i) {
#pragma unroll
                for (int k = 0; k < RR; ++k) {
                    const float w = a[i] * b[k];
                    const float c = cp[(i * RR + k) * RR + j];
                    if (i & 1) acc1 = fmaf(w, c, acc1);
                    else       acc0 = fmaf(w, c, acc0);
                }
            }
            sQ[side][combo][j] = acc0 + acc1;
        }
        __syncthreads();

        // R1[p][j] = sum_i Q1[p][i] * MT[i][j]. 160 tasks.
        if (tid < 16 * RR) {
            const int p = tid / RR;
            const int j = tid % RR;
            float acc = 0.0f;
#pragma unroll
            for (int i = 0; i < RR; ++i)
                acc = fmaf(sQ[0][p][i], sMT[i * RR + j], acc);
            sR1[p][j] = acc;
        }
        __syncthreads();

        // T[u][c=q*16+p] = sum_j R1[p][j]*Q2[q][j]; emit bf16 hi/lo split.
        if (tid < 256) {
            const int c = tid;
            const int p = c & 15, q = c >> 4;
            float acc = 0.0f;
#pragma unroll
            for (int j = 0; j < RR; ++j)
                acc = fmaf(sR1[p][j], sQ[1][q][j], acc);
            const unsigned short h = f2bf_trunc(acc);
            const unsigned short l = f2bf_trunc(acc - bf2f(h));
            Thi[u * 256 + c] = h;
            Tlo[u * 256 + c] = l;
        }
    }

    // grid-wide barrier: device-scope release/acquire makes Thi/Tlo visible.
    cg::this_grid().sync();

    // ================= phase 2: batch evaluation via MFMA =================
    // 8 waves/block: (wid&3) selects gw sub-slot, (wid>>2) selects ubase.
    // mfma_f32_16x16x32_bf16, D: row=(lane>>4)*4+reg -> batch,
    // col=lane&15 -> unit. c = s*32+kb*8+j -> q=2s+(kb>>1), p=(kb&1)*8+j.
    const int lane  = tid & 63;
    const int wid   = tid >> 6;                     // 0..7
    const int gw    = bid * 4 + (wid & 3);          // 0..1023
    const int ubase = (wid >> 2) * 16;              // 0 or 16

    const int n  = lane & 15;    // unit column / batch row owner
    const int kb = lane >> 4;    // k-block 0..3

    // hoist the full B-panel into registers (it-loop invariant).
    const unsigned short* th = Thi + (ubase + n) * 256 + kb * 8;
    const unsigned short* tl = Tlo + (ubase + n) * 256 + kb * 8;
    short8 bh[8], bl[8];
#pragma unroll
    for (int s = 0; s < 8; ++s) {
        bh[s] = *reinterpret_cast<const short8*>(th + s * 32);
        bl[s] = *reinterpret_cast<const short8*>(tl + s * 32);
    }

    const int qpar = kb >> 1;    // parity of w2 index this lane consumes
    const int kpar = kb & 1;     // which half of w1 this lane consumes

#pragma unroll
    for (int it = 0; it < ITER; ++it) {
        const int bbase = (it * NWAVE + gw) * 16;

        // per-lane w build (batch bbase+n; shared across kb groups)
        const float* xp = X + (size_t)(bbase + n) * (FF * DD);
        const float4 v0 = *reinterpret_cast<const float4*>(xp + 0);
        const float4 v1 = *reinterpret_cast<const float4*>(xp + 4);
        const float4 v2 = *reinterpret_cast<const float4*>(xp + 8);
        const float4 v3 = *reinterpret_cast<const float4*>(xp + 12);

        float t01[4], t23[4], t45[4], t67[4];
        t01[0] = v0.x * v0.z; t01[1] = v0.y * v0.z; t01[2] = v0.x * v0.w; t01[3] = v0.y * v0.w;
        t23[0] = v1.x * v1.z; t23[1] = v1.y * v1.z; t23[2] = v1.x * v1.w; t23[3] = v1.y * v1.w;
        t45[0] = v2.x * v2.z; t45[1] = v2.y * v2.z; t45[2] = v2.x * v2.w; t45[3] = v2.y * v2.w;
        t67[0] = v3.x * v3.z; t67[1] = v3.y * v3.z; t67[2] = v3.x * v3.w; t67[3] = v3.y * v3.w;

        // w1[p], p = kpar*8+j: w1[p] = t01[j&3] * t23[2*kpar + (j>>2)]
        const float v23_0 = kpar ? t23[2] : t23[0];
        const float v23_1 = kpar ? t23[3] : t23[1];
        float w1own[8];
#pragma unroll
        for (int j = 0; j < 8; ++j)
            w1own[j] = t01[j & 3] * ((j >> 2) ? v23_1 : v23_0);

        // w2[q], q = 2s+qpar: w2[q] = t45[2*(s&1)+qpar] * t67[s>>1]
        const float u45_0 = qpar ? t45[1] : t45[0];
        const float u45_1 = qpar ? t45[3] : t45[2];

        f32x4 acc0 = {0.0f, 0.0f, 0.0f, 0.0f};   // ah*bh
        f32x4 acc1 = {0.0f, 0.0f, 0.0f, 0.0f};   // al*bh
        f32x4 acc2 = {0.0f, 0.0f, 0.0f, 0.0f};   // ah*bl

#pragma unroll
        for (int s = 0; s < 8; ++s) {
            const float w2s = ((s & 1) ? u45_1 : u45_0) * t67[s >> 1];

            // bf16 split of a_j = w1own[j]*w2s, packed pairwise via v_perm.
            u32x4 ahp, alp;
#pragma unroll
            for (int e = 0; e < 4; ++e) {
                const float a0 = w1own[2 * e + 0] * w2s;
                const float a1 = w1own[2 * e + 1] * w2s;
                // hi16(a1):hi16(a0)
                ahp[e] = __builtin_amdgcn_perm(bcu(a1), bcu(a0), 0x07060302u);
                const float r0 = a0 - bcf(bcu(a0) & 0xFFFF0000u);
                const float r1 = a1 - bcf(bcu(a1) & 0xFFFF0000u);
                alp[e] = __builtin_amdgcn_perm(bcu(r1), bcu(r0), 0x07060302u);
            }
            const short8 ah = __builtin_bit_cast(short8, ahp);
            const short8 al = __builtin_bit_cast(short8, alp);

            acc0 = __builtin_amdgcn_mfma_f32_16x16x32_bf16(ah, bh[s], acc0, 0, 0, 0);
            acc1 = __builtin_amdgcn_mfma_f32_16x16x32_bf16(al, bh[s], acc1, 0, 0, 0);
            acc2 = __builtin_amdgcn_mfma_f32_16x16x32_bf16(ah, bl[s], acc2, 0, 0, 0);
        }

        // D: batch = bbase + kb*4 + r, unit = ubase + n
        float* op = out + (size_t)(bbase + kb * 4) * UU + ubase + n;
#pragma unroll
        for (int r = 0; r < 4; ++r)
            op[(size_t)r * UU] = (acc0[r] + acc1[r]) + acc2[r];
    }
}

extern "C" void kernel_launch(void* const* d_in, const int* in_sizes, int n_in,
                              void* d_out, int out_size, void* d_ws, size_t ws_size,
                              hipStream_t stream) {
    const float* X      = (const float*)d_in[0];
    const float* core11 = (const float*)d_in[1];
    const float* core12 = (const float*)d_in[2];
    const float* core13 = (const float*)d_in[3];
    const float* core14 = (const float*)d_in[4];
    const float* core21 = (const float*)d_in[5];
    const float* core22 = (const float*)d_in[6];
    const float* FM     = (const float*)d_in[7];
    const float* MT     = (const float*)d_in[8];
    float* out          = (float*)d_out;

    unsigned short* Thi = (unsigned short*)d_ws;          // 32*256*2 = 16 KB
    unsigned short* Tlo = Thi + UU * 256;                 // +16 KB

    void* args[] = {
        (void*)&X,
        (void*)&core11, (void*)&core12, (void*)&core13, (void*)&core14,
        (void*)&core21, (void*)&core22,
        (void*)&FM, (void*)&MT,
        (void*)&Thi, (void*)&Tlo,
        (void*)&out
    };
    hipLaunchCooperativeKernel((void*)fused_tree, dim3(256), dim3(512),
                               args, 0, stream);
}

// Round 7
// 84.409 us; speedup vs baseline: 1.5079x; 1.5079x over previous
//
#include <hip/hip_runtime.h>

// TensorTree collapsed to multilinear table: out[b,u] = w1(b)^T T_u w2(b),
//   out[b,u] = sum_c K[b][c] * T[u][c],  c = q*16+p,  K[c] = w1[p]*w2[q]
// Round 10: REVERT cooperative fusion (R6: +43 us — hipLaunchCooperativeKernel
// doesn't graph-replay cheaply; grid.sync serialized 224 idle blocks).
// Back to R5 two-kernel structure, plus ONE change:
//  - software-pipelined X loads in tree_eval_mfma: iteration it+1's four
//    float4 loads are issued before iteration it's pack/MFMA body, hiding
//    ~400-900 cy of L3/HBM latency under ~640 cy of compute. R5 exposed
//    this latency 4x per wave (eval 11.6 us vs ~2.5 us issue model).
// Numerics bit-identical to R5 (absmax must stay exactly 0.25).
// Precision: K=ah+al, T=Thi+Tlo, 3 MFMA products (al*bl dropped, ~2^-16).

#define BB 65536
#define FF 8
#define DD 2
#define RR 10
#define UU 32

typedef __attribute__((ext_vector_type(8))) short short8;
typedef __attribute__((ext_vector_type(4))) float f32x4;
typedef __attribute__((ext_vector_type(4))) unsigned int u32x4;

__device__ __forceinline__ unsigned short f2bf_trunc(float x) {
    return (unsigned short)(__builtin_bit_cast(unsigned int, x) >> 16);
}
__device__ __forceinline__ float bf2f(unsigned short h) {
    return __builtin_bit_cast(float, ((unsigned int)h) << 16);
}
__device__ __forceinline__ unsigned int bcu(float x) {
    return __builtin_bit_cast(unsigned int, x);
}
__device__ __forceinline__ float bcf(unsigned int x) {
    return __builtin_bit_cast(float, x);
}

// ---------------- kernel 1: precompute T (one block per unit) ----------------

__global__ __launch_bounds__(256) void precompute_T_fast(
    const float* __restrict__ core11, const float* __restrict__ core12,
    const float* __restrict__ core13, const float* __restrict__ core14,
    const float* __restrict__ core21, const float* __restrict__ core22,
    const float* __restrict__ FM, const float* __restrict__ MT,
    unsigned short* __restrict__ Thi, unsigned short* __restrict__ Tlo)
{
    const int u   = blockIdx.x;    // 0..31
    const int tid = threadIdx.x;   // 0..255

    __shared__ float sC[6][RR * RR * RR];  // staged cores, 24 KB
    __shared__ float sMT[RR * RR];
    __shared__ float sLeaf[FF][2][RR];   // [leaf][basis][r]
    __shared__ float sP[4][4][RR];       // [pair][combo(a_lo + 2*a_hi)][j]
    __shared__ float sQ[2][16][RR];      // [side][combo][j]
    __shared__ float sR1[16][RR];        // Q1 . MT

    // Phase -1: stage cores + MT into LDS, coalesced.
#pragma unroll
    for (int r = 0; r < 4; ++r) {
        const int o = tid + 256 * r;
        if (o < RR * RR * RR) {
            sC[0][o] = core11[o];
            sC[1][o] = core12[o];
            sC[2][o] = core13[o];
            sC[3][o] = core14[o];
            sC[4][o] = core21[o];
            sC[5][o] = core22[o];
        }
    }
    if (tid < RR * RR) sMT[tid] = MT[tid];

    // Phase 0: leaf basis vectors. leaf[f][a][r] = FM[a, r, f, u]
    if (tid < FF * 2 * RR) {             // 160 tasks
        const int f = tid / (2 * RR);
        const int rem = tid % (2 * RR);
        const int a = rem / RR;
        const int r = rem % RR;
        sLeaf[f][a][r] = FM[((a * RR + r) * FF + f) * UU + u];
    }
    __syncthreads();

    // Phase A: level-1 pairs. 4 pairs x 4 combos x RR j = 160 tasks.
    if (tid < 4 * 4 * RR) {
        const int P   = tid / (4 * RR);
        const int rem = tid % (4 * RR);
        const int s   = rem / RR;              // combo: a_lo + 2*a_hi
        const int j   = rem % RR;
        const int fa = 2 * P, fb = 2 * P + 1;
        const int ai = s & 1, bi = s >> 1;
        const float* cp = sC[P];
        float a[RR], b[RR];
#pragma unroll
        for (int i = 0; i < RR; ++i) { a[i] = sLeaf[fa][ai][i]; b[i] = sLeaf[fb][bi][i]; }
        float acc0 = 0.0f, acc1 = 0.0f;
#pragma unroll
        for (int i = 0; i < RR; ++i) {
#pragma unroll
            for (int k = 0; k < RR; ++k) {
                const float w = a[i] * b[k];
                const float c = cp[(i * RR + k) * RR + j];
                if (i & 1) acc1 = fmaf(w, c, acc1);
                else       acc0 = fmaf(w, c, acc0);
            }
        }
        sP[P][s][j] = acc0 + acc1;
    }
    __syncthreads();

    // Phase B: level-2. 2 sides x 16 combos x RR j = 320 tasks.
    for (int t = tid; t < 2 * 16 * RR; t += 256) {
        const int side  = t / (16 * RR);
        const int rem   = t % (16 * RR);
        const int combo = rem / RR;
        const int j     = rem % RR;
        const int pa = side * 2, pb = side * 2 + 1;
        const float* cp = sC[4 + side];
        float a[RR], b[RR];
#pragma unroll
        for (int i = 0; i < RR; ++i) {
            a[i] = sP[pa][combo & 3][i];
            b[i] = sP[pb][combo >> 2][i];
        }
        float acc0 = 0.0f, acc1 = 0.0f;
#pragma unroll
        for (int i = 0; i < RR; ++i) {
#pragma unroll
            for (int k = 0; k < RR; ++k) {
                const float w = a[i] * b[k];
                const float c = cp[(i * RR + k) * RR + j];
                if (i & 1) acc1 = fmaf(w, c, acc1);
                else       acc0 = fmaf(w, c, acc0);
            }
        }
        sQ[side][combo][j] = acc0 + acc1;
    }
    __syncthreads();

    // Phase C: R1[p][j] = sum_i Q1[p][i] * MT[i][j]. 160 tasks.
    if (tid < 16 * RR) {
        const int p = tid / RR;
        const int j = tid % RR;
        float acc = 0.0f;
#pragma unroll
        for (int i = 0; i < RR; ++i)
            acc = fmaf(sQ[0][p][i], sMT[i * RR + j], acc);
        sR1[p][j] = acc;
    }
    __syncthreads();

    // Phase D: T[u][c=q*16+p] = sum_j R1[p][j]*Q2[q][j]; emit bf16 hi/lo split.
    {
        const int c = tid;
        const int p = c & 15, q = c >> 4;
        float acc = 0.0f;
#pragma unroll
        for (int j = 0; j < RR; ++j)
            acc = fmaf(sR1[p][j], sQ[1][q][j], acc);
        const unsigned short h = f2bf_trunc(acc);
        const unsigned short l = f2bf_trunc(acc - bf2f(h));
        Thi[u * 256 + c] = h;
        Tlo[u * 256 + c] = l;
    }
}

// ---------------- kernel 2: batch evaluation via MFMA ----------------
// grid = (256, 2), block = 256 (4 waves). Each wave: 16 units (ubase +
// lane&15 column), 4 iterations x 16 batches. mfma_f32_16x16x32_bf16,
// D: row=(lane>>4)*4+reg -> batch, col=lane&15 -> unit (verified layout).
// K-index algebra: c = s*32 + kb*8 + j  ->  q = 2s+(kb>>1), p=(kb&1)*8+j.

#define NWAVE 1024   // waves per unit-group = gridDim.x * 4
#define ITER  4

__global__ __launch_bounds__(256, 2) void tree_eval_mfma(
    const float* __restrict__ X,
    const unsigned short* __restrict__ Thi,
    const unsigned short* __restrict__ Tlo,
    float* __restrict__ out)
{
    const int lane  = threadIdx.x & 63;
    const int wid   = threadIdx.x >> 6;                 // 0..3
    const int gw    = blockIdx.x * 4 + wid;             // 0..NWAVE-1
    const int ubase = blockIdx.y * 16;

    const int n  = lane & 15;    // unit column / batch row owner
    const int kb = lane >> 4;    // k-block 0..3

    // ---- hoist the full B-panel into registers (it-loop invariant) ----
    // lane holds T[ubase+n][s*32 + kb*8 + j], j=0..7, for all s.
    const unsigned short* th = Thi + (ubase + n) * 256 + kb * 8;
    const unsigned short* tl = Tlo + (ubase + n) * 256 + kb * 8;
    short8 bh[8], bl[8];
#pragma unroll
    for (int s = 0; s < 8; ++s) {
        bh[s] = *reinterpret_cast<const short8*>(th + s * 32);
        bl[s] = *reinterpret_cast<const short8*>(tl + s * 32);
    }

    const int qpar = kb >> 1;    // parity of w2 index this lane consumes
    const int kpar = kb & 1;     // which half of w1 this lane consumes

    // ---- software pipeline: preload iteration 0's X ----
    const float* xp0 = X + (size_t)(((0 * NWAVE + gw) * 16) + n) * (FF * DD);
    float4 v0 = *reinterpret_cast<const float4*>(xp0 + 0);
    float4 v1 = *reinterpret_cast<const float4*>(xp0 + 4);
    float4 v2 = *reinterpret_cast<const float4*>(xp0 + 8);
    float4 v3 = *reinterpret_cast<const float4*>(xp0 + 12);

#pragma unroll
    for (int it = 0; it < ITER; ++it) {
        const int bbase = (it * NWAVE + gw) * 16;

        // issue next iteration's loads FIRST (hide latency under this
        // iteration's pack/MFMA body)
        float4 nv0, nv1, nv2, nv3;
        if (it + 1 < ITER) {
            const float* xpn = X + (size_t)((((it + 1) * NWAVE + gw) * 16) + n) * (FF * DD);
            nv0 = *reinterpret_cast<const float4*>(xpn + 0);
            nv1 = *reinterpret_cast<const float4*>(xpn + 4);
            nv2 = *reinterpret_cast<const float4*>(xpn + 8);
            nv3 = *reinterpret_cast<const float4*>(xpn + 12);
        }

        // ---- per-lane w build (batch bbase+n; shared across kb groups) ----
        float t01[4], t23[4], t45[4], t67[4];
        t01[0] = v0.x * v0.z; t01[1] = v0.y * v0.z; t01[2] = v0.x * v0.w; t01[3] = v0.y * v0.w;
        t23[0] = v1.x * v1.z; t23[1] = v1.y * v1.z; t23[2] = v1.x * v1.w; t23[3] = v1.y * v1.w;
        t45[0] = v2.x * v2.z; t45[1] = v2.y * v2.z; t45[2] = v2.x * v2.w; t45[3] = v2.y * v2.w;
        t67[0] = v3.x * v3.z; t67[1] = v3.y * v3.z; t67[2] = v3.x * v3.w; t67[3] = v3.y * v3.w;

        // w1[p], p = kpar*8+j: w1[p] = t01[j&3] * t23[2*kpar + (j>>2)]
        const float v23_0 = kpar ? t23[2] : t23[0];
        const float v23_1 = kpar ? t23[3] : t23[1];
        float w1own[8];
#pragma unroll
        for (int j = 0; j < 8; ++j)
            w1own[j] = t01[j & 3] * ((j >> 2) ? v23_1 : v23_0);

        // w2[q], q = 2s+qpar: w2[q] = t45[2*(s&1)+qpar] * t67[s>>1]
        const float u45_0 = qpar ? t45[1] : t45[0];
        const float u45_1 = qpar ? t45[3] : t45[2];

        f32x4 acc0 = {0.0f, 0.0f, 0.0f, 0.0f};   // ah*bh
        f32x4 acc1 = {0.0f, 0.0f, 0.0f, 0.0f};   // al*bh
        f32x4 acc2 = {0.0f, 0.0f, 0.0f, 0.0f};   // ah*bl

#pragma unroll
        for (int s = 0; s < 8; ++s) {
            const float w2s = ((s & 1) ? u45_1 : u45_0) * t67[s >> 1];

            // bf16 split of a_j = w1own[j]*w2s, packed pairwise via v_perm.
            u32x4 ahp, alp;
#pragma unroll
            for (int e = 0; e < 4; ++e) {
                const float a0 = w1own[2 * e + 0] * w2s;
                const float a1 = w1own[2 * e + 1] * w2s;
                // hi16(a1):hi16(a0)
                ahp[e] = __builtin_amdgcn_perm(bcu(a1), bcu(a0), 0x07060302u);
                const float r0 = a0 - bcf(bcu(a0) & 0xFFFF0000u);
                const float r1 = a1 - bcf(bcu(a1) & 0xFFFF0000u);
                alp[e] = __builtin_amdgcn_perm(bcu(r1), bcu(r0), 0x07060302u);
            }
            const short8 ah = __builtin_bit_cast(short8, ahp);
            const short8 al = __builtin_bit_cast(short8, alp);

            acc0 = __builtin_amdgcn_mfma_f32_16x16x32_bf16(ah, bh[s], acc0, 0, 0, 0);
            acc1 = __builtin_amdgcn_mfma_f32_16x16x32_bf16(al, bh[s], acc1, 0, 0, 0);
            acc2 = __builtin_amdgcn_mfma_f32_16x16x32_bf16(ah, bl[s], acc2, 0, 0, 0);
        }

        // D: batch = bbase + kb*4 + r, unit = ubase + n
        float* op = out + (size_t)(bbase + kb * 4) * UU + ubase + n;
#pragma unroll
        for (int r = 0; r < 4; ++r)
            op[(size_t)r * UU] = (acc0[r] + acc1[r]) + acc2[r];

        // rotate pipeline registers (compile-time, SSA-renamed away)
        if (it + 1 < ITER) { v0 = nv0; v1 = nv1; v2 = nv2; v3 = nv3; }
    }
}

extern "C" void kernel_launch(void* const* d_in, const int* in_sizes, int n_in,
                              void* d_out, int out_size, void* d_ws, size_t ws_size,
                              hipStream_t stream) {
    const float* X      = (const float*)d_in[0];
    const float* core11 = (const float*)d_in[1];
    const float* core12 = (const float*)d_in[2];
    const float* core13 = (const float*)d_in[3];
    const float* core14 = (const float*)d_in[4];
    const float* core21 = (const float*)d_in[5];
    const float* core22 = (const float*)d_in[6];
    const float* FM     = (const float*)d_in[7];
    const float* MT     = (const float*)d_in[8];
    float* out          = (float*)d_out;

    unsigned short* Thi = (unsigned short*)d_ws;          // 32*256*2 = 16 KB
    unsigned short* Tlo = Thi + UU * 256;                 // +16 KB

    precompute_T_fast<<<dim3(UU), dim3(256), 0, stream>>>(
        core11, core12, core13, core14, core21, core22, FM, MT, Thi, Tlo);

    tree_eval_mfma<<<dim3(256, 2), dim3(256), 0, stream>>>(X, Thi, Tlo, out);
}